// Round 6
// baseline (197.247 us; speedup 1.0000x reference)
//
#include <hip/hip_runtime.h>
#include <hip/hip_bf16.h>

// Problem constants (fixed by setup_inputs)
constexpr int B  = 2;
constexpr int C  = 256;       // channels per level
constexpr int H0 = 100, W0 = 152;
constexpr int H1 = 50,  W1 = 76;
constexpr int H2 = 25,  W2 = 38;
constexpr int N  = 128;       // rois per batch
constexpr int K  = B * N;     // 256 rois
constexpr int OUTS = 7;      // output grid

// ws layout (bf16 elements)
constexpr size_t F0E = (size_t)B * H0 * W0 * C;  // 7,782,400
constexpr size_t F1E = (size_t)B * H1 * W1 * C;  // 1,945,600
constexpr size_t F2E = (size_t)B * H2 * W2 * C;  //   486,400

#define DEV __device__ __forceinline__

DEV float ldbf(const __hip_bfloat16* p) { return __bfloat162float(*p); }

// pack 4 channels -> 8B store
DEV void st4bf(__hip_bfloat16* p, float a, float b, float c, float d) {
  union { __hip_bfloat16 h[4]; uint2 u; } pk;
  pk.h[0] = __float2bfloat16(a); pk.h[1] = __float2bfloat16(b);
  pk.h[2] = __float2bfloat16(c); pk.h[3] = __float2bfloat16(d);
  *reinterpret_cast<uint2*>(p) = pk.u;
}

// ---------------------------------------------------------------------------
// Kernel 1: pure NCHW->BHWC transpose of the three source levels to bf16.
// No upsampling (folded into roi_kernel's composed weights).
// Blocks: [0,800) lvl0, [800,1200) lvl1, [1200,1400) lvl2; each block =
// (b, y, 64-ch tile). LDS stride odd (153/77/39) -> conflict-free reads.
// ---------------------------------------------------------------------------
__global__ __launch_bounds__(256) void transpose_kernel(
    const float* __restrict__ x0, const float* __restrict__ x1,
    const float* __restrict__ x2, __hip_bfloat16* __restrict__ f0,
    __hip_bfloat16* __restrict__ f1, __hip_bfloat16* __restrict__ f2) {
  __shared__ float buf[64 * 153];
  const int blk = blockIdx.x;
  const int t   = threadIdx.x;

  if (blk < 800) {
    const int tile = blk & 3, y = (blk >> 2) % H0, b = blk / 400;
    const int c0l = tile * 64;
    const float* src = x0 + (((size_t)b * C + c0l) * H0 + y) * W0;
    for (int i = 0; i < 10; ++i) {
      const int lin = i * 256 + t;
      if (lin < 64 * 38) {
        const int cl = lin / 38, xq = lin % 38;
        const float4 v = *reinterpret_cast<const float4*>(
            src + (size_t)cl * (H0 * W0) + xq * 4);
        float* d = &buf[cl * 153 + xq * 4];
        d[0] = v.x; d[1] = v.y; d[2] = v.z; d[3] = v.w;
      }
    }
    __syncthreads();
    __hip_bfloat16* dst = f0 + (((size_t)b * H0 + y) * W0) * C + c0l;
    for (int i = 0; i < 10; ++i) {
      const int lin = i * 256 + t;
      if (lin < W0 * 16) {
        const int x = lin >> 4, cq = lin & 15;
        st4bf(dst + (size_t)x * C + cq * 4,
              buf[(cq * 4 + 0) * 153 + x], buf[(cq * 4 + 1) * 153 + x],
              buf[(cq * 4 + 2) * 153 + x], buf[(cq * 4 + 3) * 153 + x]);
      }
    }
  } else if (blk < 1200) {
    const int j = blk - 800;
    const int tile = j & 3, y = (j >> 2) % H1, b = j / 200;
    const int c0l = tile * 64;
    const float* src = x1 + (((size_t)b * C + c0l) * H1 + y) * W1;
    for (int i = 0; i < 5; ++i) {
      const int lin = i * 256 + t;
      if (lin < 64 * 19) {
        const int cl = lin / 19, xq = lin % 19;
        const float4 v = *reinterpret_cast<const float4*>(
            src + (size_t)cl * (H1 * W1) + xq * 4);
        float* d = &buf[cl * 77 + xq * 4];
        d[0] = v.x; d[1] = v.y; d[2] = v.z; d[3] = v.w;
      }
    }
    __syncthreads();
    __hip_bfloat16* dst = f1 + (((size_t)b * H1 + y) * W1) * C + c0l;
    for (int i = 0; i < 5; ++i) {
      const int lin = i * 256 + t;
      if (lin < W1 * 16) {
        const int x = lin >> 4, cq = lin & 15;
        st4bf(dst + (size_t)x * C + cq * 4,
              buf[(cq * 4 + 0) * 77 + x], buf[(cq * 4 + 1) * 77 + x],
              buf[(cq * 4 + 2) * 77 + x], buf[(cq * 4 + 3) * 77 + x]);
      }
    }
  } else {
    const int j = blk - 1200;
    const int tile = j & 3, y = (j >> 2) % H2, b = j / 100;
    const int c0l = tile * 64;
    const float* src = x2 + (((size_t)b * C + c0l) * H2 + y) * W2;
    for (int i = 0; i < 5; ++i) {
      const int lin = i * 256 + t;
      if (lin < 64 * 19) {
        const int cl = lin / 19, xq = lin % 19;
        const float2 v = *reinterpret_cast<const float2*>(
            src + (size_t)cl * (H2 * W2) + xq * 2);
        float* d = &buf[cl * 39 + xq * 2];
        d[0] = v.x; d[1] = v.y;
      }
    }
    __syncthreads();
    __hip_bfloat16* dst = f2 + (((size_t)b * H2 + y) * W2) * C + c0l;
    for (int i = 0; i < 3; ++i) {
      const int lin = i * 256 + t;
      if (lin < W2 * 16) {
        const int x = lin >> 4, cq = lin & 15;
        st4bf(dst + (size_t)x * C + cq * 4,
              buf[(cq * 4 + 0) * 39 + x], buf[(cq * 4 + 1) * 39 + x],
              buf[(cq * 4 + 2) * 39 + x], buf[(cq * 4 + 3) * 39 + x]);
      }
    }
  }
}

// ---------------------------------------------------------------------------
// Kernel 2: RoIAlign sampling directly from the three source-resolution BHWC
// arrays. Block = (k, lvl); 768 blocks; thread t owns channel lvl*256+t for
// all 49 cells of roi k. Level 0: direct 4-corner bilinear (as before).
// Levels 1/2: upsample folded in — each feat-space corner pair expands into
// a 3-wide source stencil per axis with exactly-composed weights (corner b's
// source floor is within +1 of corner a's because the upsample step <= 0.5),
// giving a 3x3 source gather per sample. Output path unchanged: LDS [256][49]
// (stride 49 = 17 mod 32, conflict-free) -> contiguous 50KB float4 writes.
// ---------------------------------------------------------------------------
__global__ __launch_bounds__(256, 3) void roi_kernel(
    const __hip_bfloat16* __restrict__ f0, const __hip_bfloat16* __restrict__ f1,
    const __hip_bfloat16* __restrict__ f2, const float* __restrict__ boxes,
    const float* __restrict__ ratio, const float* __restrict__ offset,
    const float* __restrict__ shape, float* __restrict__ out) {
  __shared__ float lds[256 * 49];
  const int blk = blockIdx.x;
  const int lvl = blk % 3;
  const int k   = blk / 3;
  const int b   = k >> 7;      // N = 128
  const int t   = threadIdx.x;

  // scale factors (batch 0, per reference)
  const float padded_h = floorf(shape[0] * ratio[0] + 2.f * offset[0]);
  const float padded_w = floorf(shape[1] * ratio[1] + 2.f * offset[1]);
  const float sx = (float)W0 / padded_w;
  const float sy = (float)H0 / padded_h;
  // per-batch roi transform
  const float rHb = ratio[b * 2 + 0], rWb = ratio[b * 2 + 1];
  const float topb = offset[b * 2 + 0], leftb = offset[b * 2 + 1];
  const float* bx = boxes + (size_t)k * 4;
  const float x1s = (bx[0] * rWb + leftb) * sx;
  const float y1s = (bx[1] * rHb + topb) * sy;
  const float x2s = (bx[2] * rWb + leftb) * sx;
  const float y2s = (bx[3] * rHb + topb) * sy;
  const float bw = fmaxf(x2s - x1s, 1.f) / OUTS;
  const float bh = fmaxf(y2s - y1s, 1.f) / OUTS;

  if (lvl == 0) {
    // ---- level 0: direct bilinear on f0 ----
    float hx[14], lx[14];
    int xo0[14], xo1[14];
    #pragma unroll
    for (int s = 0; s < 14; ++s) {
      const float X = x1s + ((float)s * 0.5f + 0.25f) * bw;
      const bool vx = (X >= -1.f) && (X <= (float)W0);
      const float Xc = fminf(fmaxf(X, 0.f), (float)(W0 - 1));
      const float xf = floorf(Xc);
      const float l  = Xc - xf;
      const int x0i = (int)xf;
      const int x1i = min(x0i + 1, W0 - 1);
      hx[s]  = vx ? (1.f - l) : 0.f;
      lx[s]  = vx ? l : 0.f;
      xo0[s] = x0i * C;
      xo1[s] = x1i * C;
    }
    const __hip_bfloat16* fb = f0 + (size_t)b * (H0 * W0 * C) + t;
    for (int ph = 0; ph < OUTS; ++ph) {
      float acc[OUTS] = {0.f, 0.f, 0.f, 0.f, 0.f, 0.f, 0.f};
      #pragma unroll
      for (int iy = 0; iy < 2; ++iy) {
        const float Y = y1s + ((float)ph + (float)iy * 0.5f + 0.25f) * bh;
        const bool vy = (Y >= -1.f) && (Y <= (float)H0);
        const float Yc = fminf(fmaxf(Y, 0.f), (float)(H0 - 1));
        const float yf = floorf(Yc);
        const float ly = Yc - yf;
        const int y0i = (int)yf;
        const int y1i = min(y0i + 1, H0 - 1);
        const float w0 = vy ? (1.f - ly) * 0.25f : 0.f;
        const float w1 = vy ? ly * 0.25f : 0.f;
        const __hip_bfloat16* r0 = fb + (size_t)y0i * (W0 * C);
        const __hip_bfloat16* r1 = fb + (size_t)y1i * (W0 * C);
        float v00[14], v01[14], v10[14], v11[14];
        #pragma unroll
        for (int s = 0; s < 14; ++s) {
          v00[s] = ldbf(r0 + xo0[s]);
          v01[s] = ldbf(r0 + xo1[s]);
          v10[s] = ldbf(r1 + xo0[s]);
          v11[s] = ldbf(r1 + xo1[s]);
        }
        #pragma unroll
        for (int s = 0; s < 14; ++s) {
          acc[s >> 1] += w0 * (hx[s] * v00[s] + lx[s] * v01[s]) +
                         w1 * (hx[s] * v10[s] + lx[s] * v11[s]);
        }
      }
      #pragma unroll
      for (int pw = 0; pw < OUTS; ++pw) lds[t * 49 + ph * 7 + pw] = acc[pw];
    }
  } else {
    // ---- levels 1/2: upsample composed into a 3x3 source stencil ----
    const float sc = (lvl == 1) ? 0.5f : 0.25f;
    const float of = (lvl == 1) ? -0.25f : -0.375f;
    const int  Hl = (lvl == 1) ? H1 : H2;
    const int  Wl = (lvl == 1) ? W1 : W2;
    const __hip_bfloat16* fsrc =
        ((lvl == 1) ? f1 : f2) + (size_t)b * ((size_t)Hl * Wl * C) + t;

    // x-side: compose feat-space bilinear x upsample into 3 col weights
    int co0[14], co1[14], co2[14];
    float cw0[14], cw1[14], cw2[14];
    #pragma unroll
    for (int s = 0; s < 14; ++s) {
      const float X = x1s + ((float)s * 0.5f + 0.25f) * bw;
      const bool vx = (X >= -1.f) && (X <= (float)W0);
      const float Xc = fminf(fmaxf(X, 0.f), (float)(W0 - 1));
      const float xf = floorf(Xc);
      const float fr = Xc - xf;
      const int xa = (int)xf;
      const int xb = min(xa + 1, W0 - 1);
      const float hw = vx ? (1.f - fr) : 0.f;   // weight on feat col xa
      const float lw = vx ? fr : 0.f;           // weight on feat col xb
      const float sa = fminf(fmaxf((float)xa * sc + of, 0.f), (float)(Wl - 1));
      const float sb = fminf(fmaxf((float)xb * sc + of, 0.f), (float)(Wl - 1));
      const int qa = (int)sa; const float fa = sa - (float)qa;
      const int qb = (int)sb; const float fb2 = sb - (float)qb;
      const int d = qb - qa;   // 0 or 1
      cw0[s] = hw * (1.f - fa) + ((d == 0) ? lw * (1.f - fb2) : 0.f);
      cw1[s] = hw * fa + ((d == 0) ? lw * fb2 : lw * (1.f - fb2));
      cw2[s] = (d == 1) ? lw * fb2 : 0.f;
      co0[s] = qa * C;
      co1[s] = min(qa + 1, Wl - 1) * C;
      co2[s] = min(qa + 2, Wl - 1) * C;
    }

    for (int ph = 0; ph < OUTS; ++ph) {
      float acc[OUTS] = {0.f, 0.f, 0.f, 0.f, 0.f, 0.f, 0.f};
      #pragma unroll
      for (int iy = 0; iy < 2; ++iy) {
        const float Y = y1s + ((float)ph + (float)iy * 0.5f + 0.25f) * bh;
        const bool vy = (Y >= -1.f) && (Y <= (float)H0);
        const float Yc = fminf(fmaxf(Y, 0.f), (float)(H0 - 1));
        const float yf = floorf(Yc);
        const float fr = Yc - yf;
        const int ya = (int)yf;
        const int yb = min(ya + 1, H0 - 1);
        const float Aw = vy ? (1.f - fr) * 0.25f : 0.f;  // fold mean /4
        const float Bw = vy ? fr * 0.25f : 0.f;
        const float ta = fminf(fmaxf((float)ya * sc + of, 0.f), (float)(Hl - 1));
        const float tb = fminf(fmaxf((float)yb * sc + of, 0.f), (float)(Hl - 1));
        const int ra = (int)ta; const float ga = ta - (float)ra;
        const int rb = (int)tb; const float gb = tb - (float)rb;
        const int e = rb - ra;   // 0 or 1
        const float rw0 = Aw * (1.f - ga) + ((e == 0) ? Bw * (1.f - gb) : 0.f);
        const float rw1 = Aw * ga + ((e == 0) ? Bw * gb : Bw * (1.f - gb));
        const float rw2 = (e == 1) ? Bw * gb : 0.f;
        const __hip_bfloat16* p0 = fsrc + (size_t)ra * (Wl * C);
        const __hip_bfloat16* p1 = fsrc + (size_t)min(ra + 1, Hl - 1) * (Wl * C);
        const __hip_bfloat16* p2 = fsrc + (size_t)min(ra + 2, Hl - 1) * (Wl * C);
        #pragma unroll
        for (int s = 0; s < 14; ++s) {
          const float r0v = cw0[s] * ldbf(p0 + co0[s]) +
                            cw1[s] * ldbf(p0 + co1[s]) +
                            cw2[s] * ldbf(p0 + co2[s]);
          const float r1v = cw0[s] * ldbf(p1 + co0[s]) +
                            cw1[s] * ldbf(p1 + co1[s]) +
                            cw2[s] * ldbf(p1 + co2[s]);
          const float r2v = cw0[s] * ldbf(p2 + co0[s]) +
                            cw1[s] * ldbf(p2 + co1[s]) +
                            cw2[s] * ldbf(p2 + co2[s]);
          acc[s >> 1] += rw0 * r0v + rw1 * r1v + rw2 * r2v;
        }
      }
      #pragma unroll
      for (int pw = 0; pw < OUTS; ++pw) lds[t * 49 + ph * 7 + pw] = acc[pw];
    }
  }
  __syncthreads();
  // contiguous 50176B block write: out[k, lvl*256 .. +256, :, :]
  float* ob = out + (size_t)k * (768 * 49) + (size_t)lvl * (256 * 49);
  const float4* ls = reinterpret_cast<const float4*>(lds);
  float4* os = reinterpret_cast<float4*>(ob);
  for (int i = 0; i < 13; ++i) {
    const int idx = i * 256 + t;
    if (idx < 3136) os[idx] = ls[idx];
  }
}

extern "C" void kernel_launch(void* const* d_in, const int* in_sizes, int n_in,
                              void* d_out, int out_size, void* d_ws, size_t ws_size,
                              hipStream_t stream) {
  const float* x0     = (const float*)d_in[0];
  const float* x1     = (const float*)d_in[1];
  const float* x2     = (const float*)d_in[2];
  const float* boxes  = (const float*)d_in[3];
  const float* ratio  = (const float*)d_in[4];
  const float* offset = (const float*)d_in[5];
  const float* shape  = (const float*)d_in[6];
  float* out = (float*)d_out;

  __hip_bfloat16* f0 = (__hip_bfloat16*)d_ws;
  __hip_bfloat16* f1 = f0 + F0E;
  __hip_bfloat16* f2 = f1 + F1E;

  const dim3 blk(256);
  transpose_kernel<<<dim3(1400), blk, 0, stream>>>(x0, x1, x2, f0, f1, f2);
  roi_kernel<<<dim3(K * 3), blk, 0, stream>>>(f0, f1, f2, boxes, ratio,
                                              offset, shape, out);
}

// Round 7
// 142.764 us; speedup vs baseline: 1.3816x; 1.3816x over previous
//
#include <hip/hip_runtime.h>
#include <hip/hip_bf16.h>

// Problem constants (fixed by setup_inputs)
constexpr int B  = 2;
constexpr int C  = 256;       // channels per level
constexpr int H0 = 100, W0 = 152;
constexpr int H1 = 50,  W1 = 76;
constexpr int H2 = 25,  W2 = 38;
constexpr int N  = 128;       // rois per batch
constexpr int K  = B * N;     // 256 rois
constexpr int CT = 3 * C;     // 768 fused channels
constexpr int OUTS = 7;       // output grid

#define DEV __device__ __forceinline__

DEV float ldbf(const __hip_bfloat16* p) { return __bfloat162float(*p); }

// pack 8 channels -> 16B store
DEV void st8bf(__hip_bfloat16* p, const float* v) {
  union { __hip_bfloat16 h[8]; uint4 u; } pk;
  #pragma unroll
  for (int j = 0; j < 8; ++j) pk.h[j] = __float2bfloat16(v[j]);
  *reinterpret_cast<uint4*>(p) = pk.u;
}

// unpack u32 (2 packed bf16) -> 2 floats
DEV void unp(uint32_t u, float& lo, float& hi) {
  lo = __uint_as_float(u << 16);
  hi = __uint_as_float(u & 0xffff0000u);
}

// ---------------------------------------------------------------------------
// Kernel 1: fused upsample + concat + NCHW->BHWC transpose, bf16 feat.
// Block = (b, y, tile); tile in [0,12): level = tile>>2, 64-channel slice.
// Level 0: float4-coalesced transpose via LDS [64][153].
// Levels 1/2 (separable): two source rows loaded coalesced, y-lerp fused
// into LDS row buffer; write phase x-lerps from LDS.
// Write phase: 8 packed channels per lane (16B stores, half the inst count).
// ---------------------------------------------------------------------------
__global__ __launch_bounds__(256) void fuse_kernel(
    const float* __restrict__ x0, const float* __restrict__ x1,
    const float* __restrict__ x2, __hip_bfloat16* __restrict__ feat) {
  __shared__ float buf[64 * 153];   // 39.2 KB
  const int blk  = blockIdx.x;
  const int tile = blk % 12;
  const int by   = blk / 12;
  const int y    = by % H0;
  const int b    = by / H0;
  const int t    = threadIdx.x;
  const int level = tile >> 2;
  const int c0l   = (tile & 3) * 64;

  __hip_bfloat16* const orow =
      feat + (((size_t)b * H0 + y) * W0) * CT + tile * 64;

  if (level == 0) {
    const float* src = x0 + (((size_t)b * C + c0l) * H0 + y) * W0;
    for (int i = 0; i < 10; ++i) {
      const int lin = i * 256 + t;
      if (lin < 64 * 38) {
        const int cl = lin / 38, xq = lin % 38;
        const float4 v =
            *reinterpret_cast<const float4*>(src + (size_t)cl * (H0 * W0) + xq * 4);
        float* d = &buf[cl * 153 + xq * 4];
        d[0] = v.x; d[1] = v.y; d[2] = v.z; d[3] = v.w;
      }
    }
    __syncthreads();
    // write: 152 x * 8 octs = 1216 units, 8 ch / lane
    for (int i = 0; i < 5; ++i) {
      const int lin = i * 256 + t;
      if (lin < 1216) {
        const int x = lin >> 3, cq = lin & 7;
        float v[8];
        #pragma unroll
        for (int j = 0; j < 8; ++j) v[j] = buf[(cq * 8 + j) * 153 + x];
        st8bf(orow + (size_t)x * CT + cq * 8, v);
      }
    }
  } else if (level == 1) {
    const float fy = fminf(fmaxf(y * 0.5f - 0.25f, 0.f), (float)(H1 - 1));
    const int   y0i = (int)fy;
    const float ly  = fy - (float)y0i;
    const int   y1i = min(y0i + 1, H1 - 1);
    const int rstep = (y1i - y0i) * W1;
    const float* s0 = x1 + (((size_t)b * C + c0l) * H1 + y0i) * W1;
    for (int i = 0; i < 5; ++i) {
      const int lin = i * 256 + t;
      if (lin < 64 * 19) {
        const int cl = lin / 19, xq = lin % 19;
        const float* p = s0 + (size_t)cl * (H1 * W1) + xq * 4;
        const float4 v0 = *reinterpret_cast<const float4*>(p);
        const float4 v1 = *reinterpret_cast<const float4*>(p + rstep);
        float* d = &buf[cl * 81 + xq * 4];
        d[0] = v0.x + ly * (v1.x - v0.x);
        d[1] = v0.y + ly * (v1.y - v0.y);
        d[2] = v0.z + ly * (v1.z - v0.z);
        d[3] = v0.w + ly * (v1.w - v0.w);
      }
    }
    __syncthreads();
    for (int i = 0; i < 5; ++i) {
      const int lin = i * 256 + t;
      if (lin < 1216) {
        const int x = lin >> 3, cq = lin & 7;
        const float fx = fminf(fmaxf(x * 0.5f - 0.25f, 0.f), (float)(W1 - 1));
        const int   x0i = (int)fx;
        const float lx  = fx - (float)x0i;
        const int   x1i = min(x0i + 1, W1 - 1);
        const float* r = &buf[cq * 8 * 81];
        float v[8];
        #pragma unroll
        for (int j = 0; j < 8; ++j) {
          const float a = r[j * 81 + x0i], bb = r[j * 81 + x1i];
          v[j] = a + lx * (bb - a);
        }
        st8bf(orow + (size_t)x * CT + cq * 8, v);
      }
    }
  } else {
    const float fy = fminf(fmaxf(y * 0.25f - 0.375f, 0.f), (float)(H2 - 1));
    const int   y0i = (int)fy;
    const float ly  = fy - (float)y0i;
    const int   y1i = min(y0i + 1, H2 - 1);
    const int rstep = (y1i - y0i) * W2;
    const float* s0 = x2 + (((size_t)b * C + c0l) * H2 + y0i) * W2;
    for (int i = 0; i < 5; ++i) {
      const int lin = i * 256 + t;
      if (lin < 64 * 19) {
        const int cl = lin / 19, xq = lin % 19;
        const float* p = s0 + (size_t)cl * (H2 * W2) + xq * 2;
        const float2 v0 = *reinterpret_cast<const float2*>(p);
        const float2 v1 = *reinterpret_cast<const float2*>(p + rstep);
        float* d = &buf[cl * 39 + xq * 2];
        d[0] = v0.x + ly * (v1.x - v0.x);
        d[1] = v0.y + ly * (v1.y - v0.y);
      }
    }
    __syncthreads();
    for (int i = 0; i < 5; ++i) {
      const int lin = i * 256 + t;
      if (lin < 1216) {
        const int x = lin >> 3, cq = lin & 7;
        const float fx = fminf(fmaxf(x * 0.25f - 0.375f, 0.f), (float)(W2 - 1));
        const int   x0i = (int)fx;
        const float lx  = fx - (float)x0i;
        const int   x1i = min(x0i + 1, W2 - 1);
        const float* r = &buf[cq * 8 * 39];
        float v[8];
        #pragma unroll
        for (int j = 0; j < 8; ++j) {
          const float a = r[j * 39 + x0i], bb = r[j * 39 + x1i];
          v[j] = a + lx * (bb - a);
        }
        st8bf(orow + (size_t)x * CT + cq * 8, v);
      }
    }
  }
}

// ---------------------------------------------------------------------------
// Kernel 2: RoIAlign from bf16 BHWC feat. Block = (k, cg in {0,1}); 512
// blocks x 192 threads. Thread t owns the adjacent channel PAIR
// cg*384 + 2t, loaded as one u32 per corner (2 channels / load) -> gather
// instruction count halves vs 1ch/thread while per-CU MLP stays equal
// (6 waves x 56-load batches = 672 outstanding, same as before).
// LDS [384][49] f32 (75 KB, 2 blocks/CU); block output region is a
// contiguous 75 KB run -> float4 writes.
// ---------------------------------------------------------------------------
__global__ __launch_bounds__(192) void roi_kernel(
    const __hip_bfloat16* __restrict__ feat, const float* __restrict__ boxes,
    const float* __restrict__ ratio, const float* __restrict__ offset,
    const float* __restrict__ shape, float* __restrict__ out) {
  __shared__ float lds[384 * 49];
  const int blk = blockIdx.x;
  const int cg  = blk & 1;
  const int k   = blk >> 1;
  const int b   = k >> 7;      // N = 128
  const int t   = threadIdx.x;
  const int c0  = cg * 384 + 2 * t;   // channel pair base

  // scale factors (batch 0, per reference)
  const float padded_h = floorf(shape[0] * ratio[0] + 2.f * offset[0]);
  const float padded_w = floorf(shape[1] * ratio[1] + 2.f * offset[1]);
  const float sx = (float)W0 / padded_w;
  const float sy = (float)H0 / padded_h;
  // per-batch roi transform
  const float rHb = ratio[b * 2 + 0], rWb = ratio[b * 2 + 1];
  const float topb = offset[b * 2 + 0], leftb = offset[b * 2 + 1];
  const float* bx = boxes + (size_t)k * 4;
  const float x1s = (bx[0] * rWb + leftb) * sx;
  const float y1s = (bx[1] * rHb + topb) * sy;
  const float x2s = (bx[2] * rWb + leftb) * sx;
  const float y2s = (bx[3] * rHb + topb) * sy;
  const float bw = fmaxf(x2s - x1s, 1.f) / OUTS;
  const float bh = fmaxf(y2s - y1s, 1.f) / OUTS;

  // hoisted x-sample data: 14 samples, validity folded into weights
  float hx[14], lx[14];
  int xo0[14], xo1[14];   // offsets in u32 units (CT/2 = 384 per x)
  #pragma unroll
  for (int s = 0; s < 14; ++s) {
    const float X = x1s + ((float)s * 0.5f + 0.25f) * bw;
    const bool vx = (X >= -1.f) && (X <= (float)W0);
    const float Xc = fminf(fmaxf(X, 0.f), (float)(W0 - 1));
    const float xf = floorf(Xc);
    const float l  = Xc - xf;
    const int x0i = (int)xf;
    const int x1i = min(x0i + 1, W0 - 1);
    hx[s]  = vx ? (1.f - l) : 0.f;
    lx[s]  = vx ? l : 0.f;
    xo0[s] = x0i * (CT / 2);
    xo1[s] = x1i * (CT / 2);
  }

  // u32 view of feat at this thread's channel pair
  const uint32_t* fb = reinterpret_cast<const uint32_t*>(
      feat + (size_t)b * (H0 * W0 * CT) + c0);

  for (int ph = 0; ph < OUTS; ++ph) {
    float accL[OUTS] = {0.f, 0.f, 0.f, 0.f, 0.f, 0.f, 0.f};
    float accH[OUTS] = {0.f, 0.f, 0.f, 0.f, 0.f, 0.f, 0.f};
    #pragma unroll
    for (int iy = 0; iy < 2; ++iy) {
      const float Y = y1s + ((float)ph + (float)iy * 0.5f + 0.25f) * bh;
      const bool vy = (Y >= -1.f) && (Y <= (float)H0);
      const float Yc = fminf(fmaxf(Y, 0.f), (float)(H0 - 1));
      const float yf = floorf(Yc);
      const float ly = Yc - yf;
      const int y0i = (int)yf;
      const int y1i = min(y0i + 1, H0 - 1);
      const float w0 = vy ? (1.f - ly) * 0.25f : 0.f;  // fold mean /4 + vy
      const float w1 = vy ? ly * 0.25f : 0.f;
      const uint32_t* r0 = fb + (size_t)y0i * (W0 * CT / 2);
      const uint32_t* r1 = fb + (size_t)y1i * (W0 * CT / 2);
      // batch all 56 independent u32 loads (14 samples x 4 corners)
      uint32_t v00[14], v01[14], v10[14], v11[14];
      #pragma unroll
      for (int s = 0; s < 14; ++s) {
        v00[s] = r0[xo0[s]];
        v01[s] = r0[xo1[s]];
        v10[s] = r1[xo0[s]];
        v11[s] = r1[xo1[s]];
      }
      #pragma unroll
      for (int s = 0; s < 14; ++s) {
        float a00l, a00h, a01l, a01h, a10l, a10h, a11l, a11h;
        unp(v00[s], a00l, a00h);
        unp(v01[s], a01l, a01h);
        unp(v10[s], a10l, a10h);
        unp(v11[s], a11l, a11h);
        accL[s >> 1] += w0 * (hx[s] * a00l + lx[s] * a01l) +
                        w1 * (hx[s] * a10l + lx[s] * a11l);
        accH[s >> 1] += w0 * (hx[s] * a00h + lx[s] * a01h) +
                        w1 * (hx[s] * a10h + lx[s] * a11h);
      }
    }
    #pragma unroll
    for (int pw = 0; pw < OUTS; ++pw) {
      lds[(2 * t + 0) * 49 + ph * 7 + pw] = accL[pw];
      lds[(2 * t + 1) * 49 + ph * 7 + pw] = accH[pw];
    }
  }
  __syncthreads();
  // contiguous 75264B block write: 18816 floats = 4704 float4
  float* ob = out + (size_t)k * (CT * 49) + (size_t)cg * (384 * 49);
  const float4* ls = reinterpret_cast<const float4*>(lds);
  float4* os = reinterpret_cast<float4*>(ob);
  for (int i = 0; i < 25; ++i) {
    const int idx = i * 192 + t;
    if (idx < 4704) os[idx] = ls[idx];
  }
}

extern "C" void kernel_launch(void* const* d_in, const int* in_sizes, int n_in,
                              void* d_out, int out_size, void* d_ws, size_t ws_size,
                              hipStream_t stream) {
  const float* x0     = (const float*)d_in[0];
  const float* x1     = (const float*)d_in[1];
  const float* x2     = (const float*)d_in[2];
  const float* boxes  = (const float*)d_in[3];
  const float* ratio  = (const float*)d_in[4];
  const float* offset = (const float*)d_in[5];
  const float* shape  = (const float*)d_in[6];
  float* out = (float*)d_out;

  __hip_bfloat16* feat = (__hip_bfloat16*)d_ws;  // 46.7 MB BHWC bf16

  fuse_kernel<<<dim3(B * H0 * 12), dim3(256), 0, stream>>>(x0, x1, x2, feat);
  roi_kernel<<<dim3(K * 2), dim3(192), 0, stream>>>(feat, boxes, ratio,
                                                    offset, shape, out);
}